// Round 21
// baseline (131.279 us; speedup 1.0000x reference)
//
#include <hip/hip_runtime.h>
#include <stdint.h>

typedef float f32x4 __attribute__((ext_vector_type(4)));
typedef _Float16 f16;
typedef f16 f16x8 __attribute__((ext_vector_type(8)));
typedef f16 f16x4 __attribute__((ext_vector_type(4)));
typedef f16 f16x2 __attribute__((ext_vector_type(2)));

#define MFMA16(a, b, c) __builtin_amdgcn_mfma_f32_16x16x32_f16((a), (b), (c), 0, 0, 0)

__device__ __forceinline__ float fexp2(float x) {
    return __builtin_amdgcn_exp2f(x);            // raw v_exp_f32: D = 2^S0
}
__device__ __forceinline__ f16x2 cvt_pk_f16(float a, float b) {
    auto p = __builtin_amdgcn_cvt_pkrtz(a, b);   // __fp16 ext_vector(2)
    return *(f16x2*)&p;
}
__device__ __forceinline__ float max3f(float a, float b, float c) {
    return fmaxf(fmaxf(a, b), c);                // clang fuses to v_max3_f32
}

typedef __attribute__((address_space(1))) const uint32_t gu32;
typedef __attribute__((address_space(3))) uint32_t lu32;
__device__ __forceinline__ void gload_lds16(const void* g, void* l) {
    __builtin_amdgcn_global_load_lds((gu32*)g, (lu32*)l, 16, 0, 0);
}

// K tile image: per (head bh, kv-tile kt) a contiguous 4096-elem (8 KB)
// buffer; elem (row, k) at  row*64 + (((k>>3) ^ (row&7)) << 3) + (k&7).
__device__ __forceinline__ size_t kv_elem(int bh, int n, int d) {
    const int kt = n >> 6, row = n & 63;
    return ((size_t)(bh * 32 + kt)) * 4096 + row * 64 + (((d >> 3) ^ (row & 7)) << 3) + (d & 7);
}

// ---------------------------------------------------------------------------
// Kernel 1: convert fp32 inputs to fp16 (X split hi/lo; w_qkv rows permuted).
// ---------------------------------------------------------------------------
__global__ void split_inputs(const float* __restrict__ X, const float* __restrict__ Wq,
                             const float* __restrict__ Wf,
                             f16* __restrict__ Xh, f16* __restrict__ Xl,
                             f16* __restrict__ Wh, f16* __restrict__ Wfb) {
    const int tid = blockIdx.x * 256 + threadIdx.x;
    if (tid < 393216) {                       // X: 3,145,728 floats
        const float* s = X + (size_t)tid * 8;
        f16 hi[8], lo[8];
#pragma unroll
        for (int j = 0; j < 8; j += 4) {
            f32x4 v = *(const f32x4*)(s + j);
#pragma unroll
            for (int q = 0; q < 4; ++q) {
                f16 h = (f16)v[q];
                hi[j + q] = h;
                lo[j + q] = (f16)(v[q] - (float)h);
            }
        }
        *(f16x8*)(Xh + (size_t)tid * 8) = *(f16x8*)hi;
        *(f16x8*)(Xl + (size_t)tid * 8) = *(f16x8*)lo;
    } else if (tid < 614400) {                // w_qkv: row c*768+d*12+h -> c*768+h*64+d
        const int t2 = tid - 393216;
        const int row = t2 / 96;
        const int k = (t2 % 96) * 8;
        const int c = row / 768;
        const int rem = row - c * 768;
        const int d = rem / 12;
        const int h2 = rem - d * 12;
        const int cp = c * 768 + h2 * 64 + d;
        const float* s = Wq + (size_t)row * 768 + k;
        f16 hi[8];
#pragma unroll
        for (int j = 0; j < 8; j += 4) {
            f32x4 v = *(const f32x4*)(s + j);
#pragma unroll
            for (int q = 0; q < 4; ++q) hi[j + q] = (f16)v[q];
        }
        *(f16x8*)(Wh + (size_t)cp * 768 + k) = *(f16x8*)hi;
    } else {                                  // w_fc
        const int t2 = tid - 614400;
        const float* s = Wf + (size_t)t2 * 8;
        f16 hi[8];
#pragma unroll
        for (int j = 0; j < 8; j += 4) {
            f32x4 v = *(const f32x4*)(s + j);
#pragma unroll
            for (int q = 0; q < 4; ++q) hi[j + q] = (f16)v[q];
        }
        *(f16x8*)(Wfb + (size_t)t2 * 8) = *(f16x8*)hi;
    }
}

// ---------------------------------------------------------------------------
// Kernel 2: qkv GEMM, 64x128 tiles (grid (64,18)=1152 blocks, 32 KB dbuf,
// single-barrier pipeline). Q scale 8*log2(e); V written directly into the
// permuted tiled image. block 256.
// ---------------------------------------------------------------------------
__global__ __launch_bounds__(256) void qkv_gemm(
    const f16* __restrict__ Xh, const f16* __restrict__ Xl,
    const f16* __restrict__ Wh,
    f16* __restrict__ Qh, f16* __restrict__ Ql,
    f16* __restrict__ Khg, f16* __restrict__ VTg) {
    __shared__ f16 Ah[2][2048], Al[2][2048], Bh[2][4096];
    const int t = threadIdx.x;
    const int lane = t & 63, wv = t >> 6;
    const int wm = (wv >> 1) * 32, wn = (wv & 1) * 64;
    const int r = lane & 15, g = lane >> 4;
    const int bm = blockIdx.x, bn = blockIdx.y;
    const bool full = (bn < 12);   // Q/K need the x-lo pass; V doesn't

    const int lrow = lane >> 2;
    const int lk = (lane & 3) * 8;

    f32x4 acc[2][4];
#pragma unroll
    for (int i = 0; i < 2; ++i)
#pragma unroll
        for (int j = 0; j < 4; ++j) acc[i][j] = (f32x4)0.0f;

    auto stage = [&](int ksi, int buf) {
        {
            const int grow = wv * 16 + lrow;
            const size_t ga = (size_t)(bm * 64 + grow) * 768 + ksi * 32 + lk;
            gload_lds16(Xh + ga, &Ah[buf][wv * 512]);
            if (full) gload_lds16(Xl + ga, &Al[buf][wv * 512]);
        }
#pragma unroll
        for (int hh = 0; hh < 2; ++hh) {
            const int ii = wv * 2 + hh;
            const int grow = ii * 16 + lrow;
            const size_t gb = (size_t)(bn * 128 + grow) * 768 + ksi * 32 + lk;
            gload_lds16(Wh + gb, &Bh[buf][ii * 512]);
        }
    };

    stage(0, 0);
    int cur = 0;
    for (int i = 0; i < 24; ++i) {
        __syncthreads();                      // buf[cur] staged; buf[cur^1] reads done
        if (i < 23) stage(i + 1, cur ^ 1);    // in flight across the compute below

        f16x8 a_h[2], b[4];
#pragma unroll
        for (int mf = 0; mf < 2; ++mf) a_h[mf] = *(f16x8*)&Ah[cur][(wm + mf * 16 + r) * 32 + g * 8];
#pragma unroll
        for (int nf = 0; nf < 4; ++nf) b[nf] = *(f16x8*)&Bh[cur][(wn + nf * 16 + r) * 32 + g * 8];
        if (full) {
            f16x8 a_l[2];
#pragma unroll
            for (int mf = 0; mf < 2; ++mf) a_l[mf] = *(f16x8*)&Al[cur][(wm + mf * 16 + r) * 32 + g * 8];
#pragma unroll
            for (int mf = 0; mf < 2; ++mf)
#pragma unroll
                for (int nf = 0; nf < 4; ++nf) {
                    acc[mf][nf] = MFMA16(a_h[mf], b[nf], acc[mf][nf]);
                    acc[mf][nf] = MFMA16(a_l[mf], b[nf], acc[mf][nf]);
                }
        } else {
#pragma unroll
            for (int mf = 0; mf < 2; ++mf)
#pragma unroll
                for (int nf = 0; nf < 4; ++nf)
                    acc[mf][nf] = MFMA16(a_h[mf], b[nf], acc[mf][nf]);
        }
        cur ^= 1;
    }

    const int comp = bn / 6;
#pragma unroll
    for (int mf = 0; mf < 2; ++mf)
#pragma unroll
        for (int nf = 0; nf < 4; ++nf) {
            const int col = bn * 128 + wn + nf * 16 + r;
            const int h = (col >> 6) % 12;
            const int d = col & 63;
            if (comp == 2) {
                const int row0 = bm * 64 + wm + mf * 16 + g * 4;    // v=0 row
                const int b2 = row0 >> 11, n = row0 & 2047;
                const int bh = b2 * 12 + h;
                const int tile = bh * 32 + (n >> 6);
                const int kvl = n & 63;
                const int kc = kvl >> 5, u = (kvl >> 4) & 1, gl = (kvl >> 2) & 3;
                f16 o4[4];
#pragma unroll
                for (int v = 0; v < 4; ++v) o4[v] = (f16)acc[mf][nf][v];
                *(f16x4*)&VTg[(size_t)tile * 4096 + kc * 2048 + d * 32 +
                              ((gl ^ ((d >> 1) & 3)) << 3) + u * 4] = *(f16x4*)o4;
            } else {
#pragma unroll
                for (int v = 0; v < 4; ++v) {
                    const int row = bm * 64 + wm + mf * 16 + g * 4 + v;
                    const int b2 = row >> 11, n = row & 2047;
                    const int bh = b2 * 12 + h;
                    float val = acc[mf][nf][v];
                    if (comp == 0) {
                        const size_t dest = ((size_t)bh * 2048 + n) * 64 + d;
                        val *= 11.5415603629f;  // 8 * log2(e): temperature + exp2-space
                        f16 hi = (f16)val;
                        Qh[dest] = hi;
                        Ql[dest] = (f16)(val - (float)hi);
                    } else {
                        Khg[kv_elem(bh, n, d)] = (f16)val;
                    }
                }
            }
        }
}

// ---------------------------------------------------------------------------
// Kernel 3: flash attention PARTIAL (KV-split x3), NO LDS, NO BARRIERS,
// ONE q-fragment per wave (64 q-rows/block) -> VGPR ~80, 6 waves/SIMD.
// Rotated K and V loads; in-register P; transposed PV; exp2 softmax
// (v_max3 + raw v_exp); defer-max THR=8; l via ones-MFMA.
// Partials NORMALIZED (O/l). grid 2304 (= 24*3*32), block 256.
// ---------------------------------------------------------------------------
__global__ __launch_bounds__(256) void attn_partial(
    const f16* __restrict__ Qh, const f16* __restrict__ Ql,
    const f16* __restrict__ Khg, const f16* __restrict__ VTg,
    f16* __restrict__ OP, float* __restrict__ Mst, float* __restrict__ Lst) {
    const int t = threadIdx.x;
    const int lane = t & 63, wv = t >> 6;
    const int r = lane & 15, g = lane >> 4;
    const int bid = blockIdx.x;
    const int qb = bid & 31;
    const int pb = bid >> 5;          // bh*3 + part
    const int part = pb % 3;
    const int bh = pb / 3;            // 0..23
    const size_t headoff = (size_t)bh * 2048 * 64;
    const int q0w = qb * 64 + wv * 16;
    const int kt0 = part * 11;
    const int nt = (part == 2) ? 10 : 11;

    const int ksw0 = ((g ^ (r & 7)) << 3);            // kc=0 K swizzle
    const int ksw1 = (((4 + g) ^ (r & 7)) << 3);      // kc=1 K swizzle
    const int vsw = ((g ^ ((r >> 1) & 3)) << 3);      // V swizzle
    const int krow = r * 64;
    const int vrow = r * 32;

    // Q fragments (B-operand): lane (r,g) holds Q[q0w+r][kc*32+g*8..+7]
    f16x8 qh[2], ql[2];
#pragma unroll
    for (int kc = 0; kc < 2; ++kc) {
        const size_t off = headoff + (size_t)(q0w + r) * 64 + kc * 32 + g * 8;
        qh[kc] = *(const f16x8*)(Qh + off);
        ql[kc] = *(const f16x8*)(Ql + off);
    }

    // o_accT[df]: lane (r,g) reg v holds O[q0w+r][df*16+g*4+v]
    // lacc: lane (r,g) holds l[q0w+r] in lacc[0] (ones-MFMA)
    f32x4 o_accT[4], lacc = (f32x4)0.0f;
    float m_run = -1e30f;
#pragma unroll
    for (int df = 0; df < 4; ++df) o_accT[df] = (f32x4)0.0f;
    const f16x8 ones8 = {(f16)1.0f, (f16)1.0f, (f16)1.0f, (f16)1.0f,
                         (f16)1.0f, (f16)1.0f, (f16)1.0f, (f16)1.0f};

    f16x8 ka0[4], ka1[4], vb[2][4];
    auto loadK = [&](int kt) {
        const f16* Ka = Khg + (size_t)(bh * 32 + kt) * 4096 + krow;
        const f16* Kb = Ka + 2048;
#pragma unroll
        for (int cf = 0; cf < 2; ++cf) {
            ka0[cf] = *(const f16x8*)(Ka + cf * 1024 + ksw0);
            ka1[cf] = *(const f16x8*)(Ka + cf * 1024 + ksw1);
            ka0[cf + 2] = *(const f16x8*)(Kb + cf * 1024 + ksw0);
            ka1[cf + 2] = *(const f16x8*)(Kb + cf * 1024 + ksw1);
        }
    };
    auto loadV = [&](int kt) {
        const f16* Va = VTg + (size_t)(bh * 32 + kt) * 4096 + vrow;
#pragma unroll
        for (int df = 0; df < 4; ++df) {
            vb[0][df] = *(const f16x8*)(Va + df * 512 + vsw);
            vb[1][df] = *(const f16x8*)(Va + 2048 + df * 512 + vsw);
        }
    };

    loadK(kt0);
    loadV(kt0);
    for (int i = 0; i < nt; ++i) {
        const int kt = kt0 + i;

        // ---- S^T = K Q^T : lane (r,g) gets S[q=r][k=cf*16+g*4+v]
        f32x4 s[4];
#pragma unroll
        for (int cf = 0; cf < 4; ++cf) s[cf] = (f32x4)0.0f;
#pragma unroll
        for (int cf = 0; cf < 4; ++cf) {
            s[cf] = MFMA16(ka0[cf], qh[0], s[cf]);
            s[cf] = MFMA16(ka0[cf], ql[0], s[cf]);
            s[cf] = MFMA16(ka1[cf], qh[1], s[cf]);
            s[cf] = MFMA16(ka1[cf], ql[1], s[cf]);
        }

        // ---- rotated K prefetch for next tile (regs just consumed)
        if (i + 1 < nt) loadK(kt + 1);

        // ---- exp2-space online softmax (v_max3 tree + raw v_exp), defer-max
        const float t0 = max3f(s[0][0], s[0][1], s[0][2]);
        const float t1 = max3f(s[0][3], s[1][0], s[1][1]);
        const float t2 = max3f(s[1][2], s[1][3], s[2][0]);
        const float t3 = max3f(s[2][1], s[2][2], s[2][3]);
        const float t4 = max3f(s[3][0], s[3][1], s[3][2]);
        float mx = fmaxf(max3f(t0, t1, t2), max3f(t3, t4, s[3][3]));
        mx = fmaxf(mx, __shfl_xor(mx, 16));
        mx = fmaxf(mx, __shfl_xor(mx, 32));
        if (__any(mx - m_run > 8.0f)) {
            const float mn = fmaxf(m_run, mx);
            const float sc = fexp2(m_run - mn);
            m_run = mn;
            lacc *= sc;
#pragma unroll
            for (int df = 0; df < 4; ++df) o_accT[df] *= sc;
        }
        const float mr = m_run;
        f16x8 pa[2];
        {
            union { f16x8 v8; f16x2 v2[4]; } pk[2];
#pragma unroll
            for (int cf = 0; cf < 4; ++cf) {
                const float p0 = fexp2(s[cf][0] - mr);
                const float p1 = fexp2(s[cf][1] - mr);
                const float p2 = fexp2(s[cf][2] - mr);
                const float p3 = fexp2(s[cf][3] - mr);
                pk[cf >> 1].v2[(cf & 1) * 2]     = cvt_pk_f16(p0, p1);
                pk[cf >> 1].v2[(cf & 1) * 2 + 1] = cvt_pk_f16(p2, p3);
            }
            pa[0] = pk[0].v8;
            pa[1] = pk[1].v8;
        }

        // ---- O^T += V^T @ P^T ; l += 1 @ P^T (ones-MFMA row-sum)
#pragma unroll
        for (int kc = 0; kc < 2; ++kc) {
#pragma unroll
            for (int df = 0; df < 4; ++df)
                o_accT[df] = MFMA16(vb[kc][df], pa[kc], o_accT[df]);
            lacc = MFMA16(ones8, pa[kc], lacc);
        }

        // ---- rotated V prefetch for next tile (vb just consumed)
        if (i + 1 < nt) loadV(kt + 1);
    }

    // ---- write partial: NORMALIZED O/l (fp16, b64 per lane) + m,l stats
    {
        const int n = q0w + r;
        const float lq = lacc[0];
        if (g == 0) {
            Mst[pb * 2048 + n] = m_run;
            Lst[pb * 2048 + n] = lq;
        }
        const float linv = 1.0f / lq;
#pragma unroll
        for (int df = 0; df < 4; ++df) {
            f16 o4[4];
#pragma unroll
            for (int v = 0; v < 4; ++v) o4[v] = (f16)(o_accT[df][v] * linv);
            *(f16x4*)&OP[((size_t)pb * 2048 + n) * 64 + df * 16 + g * 4] = *(f16x4*)o4;
        }
    }
}

// ---------------------------------------------------------------------------
// Kernel 3b: combine the three KV-parts -> AO [b, n, h*64+d] fp16.
// ---------------------------------------------------------------------------
__global__ void attn_combine(const f16* __restrict__ OP, const float* __restrict__ Mst,
                             const float* __restrict__ Lst, f16* __restrict__ AO) {
    const int tid = blockIdx.x * 256 + threadIdx.x;
    const int d4 = (tid & 15) * 4;
    const int pr = tid >> 4;          // bh*2048 + n
    const int bh = pr >> 11, n = pr & 2047;
    const int i0 = (bh * 3) * 2048 + n;
    const float m0 = Mst[i0], m1 = Mst[i0 + 2048], m2 = Mst[i0 + 4096];
    const float m = max3f(m0, m1, m2);
    const float c0 = fexp2(m0 - m) * Lst[i0];
    const float c1 = fexp2(m1 - m) * Lst[i0 + 2048];
    const float c2 = fexp2(m2 - m) * Lst[i0 + 4096];
    const float inv = 1.0f / (c0 + c1 + c2);
    f16x4 o0 = *(const f16x4*)(OP + (size_t)i0 * 64 + d4);
    f16x4 o1 = *(const f16x4*)(OP + (size_t)(i0 + 2048) * 64 + d4);
    f16x4 o2 = *(const f16x4*)(OP + (size_t)(i0 + 4096) * 64 + d4);
    const int b = bh / 12, h = bh - b * 12;
    f16 out[4];
#pragma unroll
    for (int j = 0; j < 4; ++j)
        out[j] = (f16)((c0 * (float)o0[j] + c1 * (float)o1[j] + c2 * (float)o2[j]) * inv);
    *(f16x4*)(AO + ((size_t)(b * 2048 + n)) * 768 + h * 64 + d4) = *(f16x4*)out;
}

// ---------------------------------------------------------------------------
// Kernel 4: out = AO @ Wfb^T + b_fc. 64x64 tiles, XOR-swizzled dbuf LDS,
// single-barrier pipeline. grid (64,12).
// ---------------------------------------------------------------------------
__global__ __launch_bounds__(256) void fc_gemm(const f16* __restrict__ A,
                                               const f16* __restrict__ Wfb,
                                               const float* __restrict__ bias,
                                               float* __restrict__ OUT) {
    __shared__ f16 As[2][64 * 64], Bs[2][64 * 64];
    const int t = threadIdx.x;
    const int lane = t & 63, wv = t >> 6;
    const int wm = (wv >> 1) * 32, wn = (wv & 1) * 32;
    const int r = lane & 15, g = lane >> 4;
    const int bm = blockIdx.x, bn = blockIdx.y;

    f32x4 acc[2][2];
#pragma unroll
    for (int i = 0; i < 2; ++i)
#pragma unroll
        for (int j = 0; j < 2; ++j) acc[i][j] = (f32x4)0.0f;

    const int srow = t >> 2;
    const int ssg = (t & 3) * 2;

    auto stage = [&](int ks, int buf) {
        const f16* as = A + (size_t)(bm * 64 + srow) * 768 + ks;
        const f16* bs = Wfb + (size_t)(bn * 64 + srow) * 768 + ks;
#pragma unroll
        for (int u = 0; u < 2; ++u) {
            const int sg = ssg + u;
            const int dst = srow * 64 + ((sg ^ (srow & 7)) << 3);
            *(f16x8*)&As[buf][dst] = *(const f16x8*)(as + sg * 8);
            *(f16x8*)&Bs[buf][dst] = *(const f16x8*)(bs + sg * 8);
        }
    };

    stage(0, 0);
    int cur = 0;
    for (int i = 0; i < 12; ++i) {
        __syncthreads();                       // buf[cur] staged; buf[cur^1] free
        if (i < 11) stage((i + 1) * 64, cur ^ 1);

#pragma unroll
        for (int kc = 0; kc < 2; ++kc) {
            f16x8 a[2], b[2];
#pragma unroll
            for (int mf = 0; mf < 2; ++mf) {
                const int row = wm + mf * 16 + r;
                a[mf] = *(f16x8*)&As[cur][row * 64 + (((kc * 4 + g) ^ (row & 7)) << 3)];
            }
#pragma unroll
            for (int nf = 0; nf < 2; ++nf) {
                const int row = wn + nf * 16 + r;
                b[nf] = *(f16x8*)&Bs[cur][row * 64 + (((kc * 4 + g) ^ (row & 7)) << 3)];
            }
#pragma unroll
            for (int mf = 0; mf < 2; ++mf)
#pragma unroll
                for (int nf = 0; nf < 2; ++nf)
                    acc[mf][nf] = MFMA16(a[mf], b[nf], acc[mf][nf]);
        }
        cur ^= 1;
    }

#pragma unroll
    for (int nf = 0; nf < 2; ++nf) {
        const int col = bn * 64 + wn + nf * 16 + r;
        const float bv = bias[col];
#pragma unroll
        for (int mf = 0; mf < 2; ++mf) {
            const int row = bm * 64 + wm + mf * 16 + g * 4;
#pragma unroll
            for (int v = 0; v < 4; ++v)
                OUT[(size_t)(row + v) * 768 + col] = acc[mf][nf][v] + bv;
        }
    }
}

// ---------------------------------------------------------------------------
extern "C" void kernel_launch(void* const* d_in, const int* in_sizes, int n_in,
                              void* d_out, int out_size, void* d_ws, size_t ws_size,
                              hipStream_t stream) {
    (void)in_sizes; (void)n_in; (void)out_size; (void)ws_size;
    const float* x     = (const float*)d_in[0];   // [2,2048,768]
    const float* w_qkv = (const float*)d_in[1];   // [2304,768]
    const float* w_fc  = (const float*)d_in[2];   // [768,768]
    const float* b_fc  = (const float*)d_in[3];   // [768]
    float* out = (float*)d_out;                   // [2,2048,768] fp32

    char* ws = (char*)d_ws;
    f16* Xh  = (f16*)ws;                         // 3,145,728 f16 each (6 MB):
    f16* Xl  = Xh + 3145728;
    f16* Qh  = Xl + 3145728;
    f16* Ql  = Qh + 3145728;
    f16* Khg = Ql + 3145728;
    f16* VTg = Khg + 3145728;
    f16* AO  = VTg + 3145728;
    f16* Wh  = AO + 3145728;                     // 1,769,472 f16
    f16* Wfb = Wh + 1769472;                     // 589,824 f16
    float* Mst = (float*)(Wfb + 589824);         // 147,456 floats (72 x 2048)
    float* Lst = Mst + 147456;
    f16* OP  = (f16*)(Lst + 147456);             // 9,437,184 f16
    // total = 68,812,800 B

    split_inputs<<<2688, 256, 0, stream>>>(x, w_qkv, w_fc, Xh, Xl, Wh, Wfb);
    qkv_gemm<<<dim3(64, 18), 256, 0, stream>>>(Xh, Xl, Wh, Qh, Ql, Khg, VTg);
    attn_partial<<<2304, 256, 0, stream>>>(Qh, Ql, Khg, VTg, OP, Mst, Lst);
    attn_combine<<<3072, 256, 0, stream>>>(OP, Mst, Lst, AO);
    fc_gemm<<<dim3(64, 12), 256, 0, stream>>>(AO, Wfb, b_fc, out);
}

// Round 22
// 119.255 us; speedup vs baseline: 1.1008x; 1.1008x over previous
//
#include <hip/hip_runtime.h>
#include <stdint.h>

typedef float f32x4 __attribute__((ext_vector_type(4)));
typedef _Float16 f16;
typedef f16 f16x8 __attribute__((ext_vector_type(8)));
typedef f16 f16x4 __attribute__((ext_vector_type(4)));
typedef f16 f16x2 __attribute__((ext_vector_type(2)));

#define MFMA16(a, b, c) __builtin_amdgcn_mfma_f32_16x16x32_f16((a), (b), (c), 0, 0, 0)

__device__ __forceinline__ float fexp2(float x) {
    return __builtin_amdgcn_exp2f(x);            // raw v_exp_f32: D = 2^S0
}
__device__ __forceinline__ f16x2 cvt_pk_f16(float a, float b) {
    auto p = __builtin_amdgcn_cvt_pkrtz(a, b);   // __fp16 ext_vector(2)
    return *(f16x2*)&p;
}
__device__ __forceinline__ float max3f(float a, float b, float c) {
    return fmaxf(fmaxf(a, b), c);                // clang fuses to v_max3_f32
}

typedef __attribute__((address_space(1))) const uint32_t gu32;
typedef __attribute__((address_space(3))) uint32_t lu32;
__device__ __forceinline__ void gload_lds16(const void* g, void* l) {
    __builtin_amdgcn_global_load_lds((gu32*)g, (lu32*)l, 16, 0, 0);
}

// K tile image: per (head bh, kv-tile kt) a contiguous 4096-elem (8 KB)
// buffer; elem (row, k) at  row*64 + (((k>>3) ^ (row&7)) << 3) + (k&7).
__device__ __forceinline__ size_t kv_elem(int bh, int n, int d) {
    const int kt = n >> 6, row = n & 63;
    return ((size_t)(bh * 32 + kt)) * 4096 + row * 64 + (((d >> 3) ^ (row & 7)) << 3) + (d & 7);
}

// ---------------------------------------------------------------------------
// Kernel 1: convert fp32 inputs to fp16 (X split hi/lo; w_qkv rows permuted).
// ---------------------------------------------------------------------------
__global__ void split_inputs(const float* __restrict__ X, const float* __restrict__ Wq,
                             const float* __restrict__ Wf,
                             f16* __restrict__ Xh, f16* __restrict__ Xl,
                             f16* __restrict__ Wh, f16* __restrict__ Wfb) {
    const int tid = blockIdx.x * 256 + threadIdx.x;
    if (tid < 393216) {                       // X: 3,145,728 floats
        const float* s = X + (size_t)tid * 8;
        f16 hi[8], lo[8];
#pragma unroll
        for (int j = 0; j < 8; j += 4) {
            f32x4 v = *(const f32x4*)(s + j);
#pragma unroll
            for (int q = 0; q < 4; ++q) {
                f16 h = (f16)v[q];
                hi[j + q] = h;
                lo[j + q] = (f16)(v[q] - (float)h);
            }
        }
        *(f16x8*)(Xh + (size_t)tid * 8) = *(f16x8*)hi;
        *(f16x8*)(Xl + (size_t)tid * 8) = *(f16x8*)lo;
    } else if (tid < 614400) {                // w_qkv: row c*768+d*12+h -> c*768+h*64+d
        const int t2 = tid - 393216;
        const int row = t2 / 96;
        const int k = (t2 % 96) * 8;
        const int c = row / 768;
        const int rem = row - c * 768;
        const int d = rem / 12;
        const int h2 = rem - d * 12;
        const int cp = c * 768 + h2 * 64 + d;
        const float* s = Wq + (size_t)row * 768 + k;
        f16 hi[8];
#pragma unroll
        for (int j = 0; j < 8; j += 4) {
            f32x4 v = *(const f32x4*)(s + j);
#pragma unroll
            for (int q = 0; q < 4; ++q) hi[j + q] = (f16)v[q];
        }
        *(f16x8*)(Wh + (size_t)cp * 768 + k) = *(f16x8*)hi;
    } else {                                  // w_fc
        const int t2 = tid - 614400;
        const float* s = Wf + (size_t)t2 * 8;
        f16 hi[8];
#pragma unroll
        for (int j = 0; j < 8; j += 4) {
            f32x4 v = *(const f32x4*)(s + j);
#pragma unroll
            for (int q = 0; q < 4; ++q) hi[j + q] = (f16)v[q];
        }
        *(f16x8*)(Wfb + (size_t)t2 * 8) = *(f16x8*)hi;
    }
}

// ---------------------------------------------------------------------------
// Kernel 2: qkv GEMM, 64x128 tiles for TLP (grid (64,18) = 1152 blocks,
// 32 KB dbuf LDS). Single-barrier pipeline. Q epilogue scale = 8*log2(e);
// V written directly into the permuted tiled image. block 256.
// ---------------------------------------------------------------------------
__global__ __launch_bounds__(256) void qkv_gemm(
    const f16* __restrict__ Xh, const f16* __restrict__ Xl,
    const f16* __restrict__ Wh,
    f16* __restrict__ Qh, f16* __restrict__ Ql,
    f16* __restrict__ Khg, f16* __restrict__ VTg) {
    __shared__ f16 Ah[2][2048], Al[2][2048], Bh[2][4096];
    const int t = threadIdx.x;
    const int lane = t & 63, wv = t >> 6;
    const int wm = (wv >> 1) * 32, wn = (wv & 1) * 64;
    const int r = lane & 15, g = lane >> 4;
    const int bm = blockIdx.x, bn = blockIdx.y;
    const bool full = (bn < 12);   // Q/K need the x-lo pass; V doesn't

    const int lrow = lane >> 2;
    const int lk = (lane & 3) * 8;

    f32x4 acc[2][4];
#pragma unroll
    for (int i = 0; i < 2; ++i)
#pragma unroll
        for (int j = 0; j < 4; ++j) acc[i][j] = (f32x4)0.0f;

    auto stage = [&](int ksi, int buf) {
        {
            const int grow = wv * 16 + lrow;
            const size_t ga = (size_t)(bm * 64 + grow) * 768 + ksi * 32 + lk;
            gload_lds16(Xh + ga, &Ah[buf][wv * 512]);
            if (full) gload_lds16(Xl + ga, &Al[buf][wv * 512]);
        }
#pragma unroll
        for (int hh = 0; hh < 2; ++hh) {
            const int ii = wv * 2 + hh;
            const int grow = ii * 16 + lrow;
            const size_t gb = (size_t)(bn * 128 + grow) * 768 + ksi * 32 + lk;
            gload_lds16(Wh + gb, &Bh[buf][ii * 512]);
        }
    };

    stage(0, 0);
    int cur = 0;
    for (int i = 0; i < 24; ++i) {
        __syncthreads();                      // buf[cur] staged; buf[cur^1] reads done
        if (i < 23) stage(i + 1, cur ^ 1);    // in flight across the compute below

        f16x8 a_h[2], b[4];
#pragma unroll
        for (int mf = 0; mf < 2; ++mf) a_h[mf] = *(f16x8*)&Ah[cur][(wm + mf * 16 + r) * 32 + g * 8];
#pragma unroll
        for (int nf = 0; nf < 4; ++nf) b[nf] = *(f16x8*)&Bh[cur][(wn + nf * 16 + r) * 32 + g * 8];
        if (full) {
            f16x8 a_l[2];
#pragma unroll
            for (int mf = 0; mf < 2; ++mf) a_l[mf] = *(f16x8*)&Al[cur][(wm + mf * 16 + r) * 32 + g * 8];
#pragma unroll
            for (int mf = 0; mf < 2; ++mf)
#pragma unroll
                for (int nf = 0; nf < 4; ++nf) {
                    acc[mf][nf] = MFMA16(a_h[mf], b[nf], acc[mf][nf]);
                    acc[mf][nf] = MFMA16(a_l[mf], b[nf], acc[mf][nf]);
                }
        } else {
#pragma unroll
            for (int mf = 0; mf < 2; ++mf)
#pragma unroll
                for (int nf = 0; nf < 4; ++nf)
                    acc[mf][nf] = MFMA16(a_h[mf], b[nf], acc[mf][nf]);
        }
        cur ^= 1;
    }

    const int comp = bn / 6;
#pragma unroll
    for (int mf = 0; mf < 2; ++mf)
#pragma unroll
        for (int nf = 0; nf < 4; ++nf) {
            const int col = bn * 128 + wn + nf * 16 + r;
            const int h = (col >> 6) % 12;
            const int d = col & 63;
            if (comp == 2) {
                // V: fused transpose into permuted tiled image, f16x4 store
                const int row0 = bm * 64 + wm + mf * 16 + g * 4;    // v=0 row
                const int b2 = row0 >> 11, n = row0 & 2047;
                const int bh = b2 * 12 + h;
                const int tile = bh * 32 + (n >> 6);
                const int kvl = n & 63;
                const int kc = kvl >> 5, u = (kvl >> 4) & 1, gl = (kvl >> 2) & 3;
                f16 o4[4];
#pragma unroll
                for (int v = 0; v < 4; ++v) o4[v] = (f16)acc[mf][nf][v];
                *(f16x4*)&VTg[(size_t)tile * 4096 + kc * 2048 + d * 32 +
                              ((gl ^ ((d >> 1) & 3)) << 3) + u * 4] = *(f16x4*)o4;
            } else {
#pragma unroll
                for (int v = 0; v < 4; ++v) {
                    const int row = bm * 64 + wm + mf * 16 + g * 4 + v;
                    const int b2 = row >> 11, n = row & 2047;
                    const int bh = b2 * 12 + h;
                    float val = acc[mf][nf][v];
                    if (comp == 0) {
                        const size_t dest = ((size_t)bh * 2048 + n) * 64 + d;
                        val *= 11.5415603629f;  // 8 * log2(e): temperature + exp2-space
                        f16 hi = (f16)val;
                        Qh[dest] = hi;
                        Ql[dest] = (f16)(val - (float)hi);
                    } else {
                        Khg[kv_elem(bh, n, d)] = (f16)val;
                    }
                }
            }
        }
}

// ---------------------------------------------------------------------------
// Kernel 3: flash attention PARTIAL (KV-split x3), NO LDS, NO BARRIERS,
// TWO q-fragments per wave. Rotated K loads (V loads mid-iteration).
// In-register P, transposed PV, exp2 softmax (v_max3 + raw v_exp),
// defer-max THR=8, l via ones-MFMA. Partials NORMALIZED (O/l).
// grid 1152, block 256. (R18/R17 exact)
// ---------------------------------------------------------------------------
__global__ __launch_bounds__(256) void attn_partial(
    const f16* __restrict__ Qh, const f16* __restrict__ Ql,
    const f16* __restrict__ Khg, const f16* __restrict__ VTg,
    f16* __restrict__ OP, float* __restrict__ Mst, float* __restrict__ Lst) {
    const int t = threadIdx.x;
    const int lane = t & 63, wv = t >> 6;
    const int r = lane & 15, g = lane >> 4;
    const int bid = blockIdx.x;
    const int qb = bid & 15;
    const int pb = bid >> 4;          // bh*3 + part
    const int part = pb % 3;
    const int bh = pb / 3;            // 0..23
    const size_t headoff = (size_t)bh * 2048 * 64;
    const int q0w = qb * 128 + wv * 32;
    const int kt0 = part * 11;
    const int nt = (part == 2) ? 10 : 11;

    const int ksw0 = ((g ^ (r & 7)) << 3);            // kc=0 K swizzle
    const int ksw1 = (((4 + g) ^ (r & 7)) << 3);      // kc=1 K swizzle
    const int vsw = ((g ^ ((r >> 1) & 3)) << 3);      // V swizzle
    const int krow = r * 64;
    const int vrow = r * 32;

    f16x8 qh[2][2], ql[2][2];
#pragma unroll
    for (int qf = 0; qf < 2; ++qf)
#pragma unroll
        for (int kc = 0; kc < 2; ++kc) {
            const size_t off = headoff + (size_t)(q0w + qf * 16 + r) * 64 + kc * 32 + g * 8;
            qh[qf][kc] = *(const f16x8*)(Qh + off);
            ql[qf][kc] = *(const f16x8*)(Ql + off);
        }

    f32x4 o_accT[2][4], lacc[2];
    float m_run[2] = {-1e30f, -1e30f};
#pragma unroll
    for (int qf = 0; qf < 2; ++qf) {
        lacc[qf] = (f32x4)0.0f;
#pragma unroll
        for (int df = 0; df < 4; ++df) o_accT[qf][df] = (f32x4)0.0f;
    }
    const f16x8 ones8 = {(f16)1.0f, (f16)1.0f, (f16)1.0f, (f16)1.0f,
                         (f16)1.0f, (f16)1.0f, (f16)1.0f, (f16)1.0f};

    f16x8 ka0[4], ka1[4];
    auto loadK = [&](int kt) {
        const f16* Ka = Khg + (size_t)(bh * 32 + kt) * 4096 + krow;
        const f16* Kb = Ka + 2048;
#pragma unroll
        for (int cf = 0; cf < 2; ++cf) {
            ka0[cf] = *(const f16x8*)(Ka + cf * 1024 + ksw0);
            ka1[cf] = *(const f16x8*)(Ka + cf * 1024 + ksw1);
            ka0[cf + 2] = *(const f16x8*)(Kb + cf * 1024 + ksw0);
            ka1[cf + 2] = *(const f16x8*)(Kb + cf * 1024 + ksw1);
        }
    };

    loadK(kt0);
    for (int i = 0; i < nt; ++i) {
        const int kt = kt0 + i;
        const f16* Va = VTg + (size_t)(bh * 32 + kt) * 4096 + vrow;

        f32x4 s[2][4];
#pragma unroll
        for (int qf = 0; qf < 2; ++qf)
#pragma unroll
            for (int cf = 0; cf < 4; ++cf) s[qf][cf] = (f32x4)0.0f;
#pragma unroll
        for (int cf = 0; cf < 4; ++cf)
#pragma unroll
            for (int qf = 0; qf < 2; ++qf) {
                s[qf][cf] = MFMA16(ka0[cf], qh[qf][0], s[qf][cf]);
                s[qf][cf] = MFMA16(ka0[cf], ql[qf][0], s[qf][cf]);
                s[qf][cf] = MFMA16(ka1[cf], qh[qf][1], s[qf][cf]);
                s[qf][cf] = MFMA16(ka1[cf], ql[qf][1], s[qf][cf]);
            }

        f16x8 vb[2][4];
#pragma unroll
        for (int df = 0; df < 4; ++df) {
            vb[0][df] = *(const f16x8*)(Va + df * 512 + vsw);
            vb[1][df] = *(const f16x8*)(Va + 2048 + df * 512 + vsw);
        }
        if (i + 1 < nt) loadK(kt + 1);

        f16x8 pa[2][2];
#pragma unroll
        for (int qf = 0; qf < 2; ++qf) {
            const float t0 = max3f(s[qf][0][0], s[qf][0][1], s[qf][0][2]);
            const float t1 = max3f(s[qf][0][3], s[qf][1][0], s[qf][1][1]);
            const float t2 = max3f(s[qf][1][2], s[qf][1][3], s[qf][2][0]);
            const float t3 = max3f(s[qf][2][1], s[qf][2][2], s[qf][2][3]);
            const float t4 = max3f(s[qf][3][0], s[qf][3][1], s[qf][3][2]);
            float mx = fmaxf(max3f(t0, t1, t2), max3f(t3, t4, s[qf][3][3]));
            mx = fmaxf(mx, __shfl_xor(mx, 16));
            mx = fmaxf(mx, __shfl_xor(mx, 32));
            if (__any(mx - m_run[qf] > 8.0f)) {
                const float mn = fmaxf(m_run[qf], mx);
                const float sc = fexp2(m_run[qf] - mn);
                m_run[qf] = mn;
                lacc[qf] *= sc;
#pragma unroll
                for (int df = 0; df < 4; ++df) o_accT[qf][df] *= sc;
            }
            const float mr = m_run[qf];
            union { f16x8 v8; f16x2 v2[4]; } pk[2];
#pragma unroll
            for (int cf = 0; cf < 4; ++cf) {
                const float p0 = fexp2(s[qf][cf][0] - mr);
                const float p1 = fexp2(s[qf][cf][1] - mr);
                const float p2 = fexp2(s[qf][cf][2] - mr);
                const float p3 = fexp2(s[qf][cf][3] - mr);
                pk[cf >> 1].v2[(cf & 1) * 2]     = cvt_pk_f16(p0, p1);
                pk[cf >> 1].v2[(cf & 1) * 2 + 1] = cvt_pk_f16(p2, p3);
            }
            pa[qf][0] = pk[0].v8;
            pa[qf][1] = pk[1].v8;
        }

#pragma unroll
        for (int kc = 0; kc < 2; ++kc) {
#pragma unroll
            for (int df = 0; df < 4; ++df)
#pragma unroll
                for (int qf = 0; qf < 2; ++qf)
                    o_accT[qf][df] = MFMA16(vb[kc][df], pa[qf][kc], o_accT[qf][df]);
#pragma unroll
            for (int qf = 0; qf < 2; ++qf)
                lacc[qf] = MFMA16(ones8, pa[qf][kc], lacc[qf]);
        }
    }

#pragma unroll
    for (int qf = 0; qf < 2; ++qf) {
        const int n = q0w + qf * 16 + r;
        const float lq = lacc[qf][0];
        if (g == 0) {
            Mst[pb * 2048 + n] = m_run[qf];
            Lst[pb * 2048 + n] = lq;
        }
        const float linv = 1.0f / lq;
#pragma unroll
        for (int df = 0; df < 4; ++df) {
            f16 o4[4];
#pragma unroll
            for (int v = 0; v < 4; ++v) o4[v] = (f16)(o_accT[qf][df][v] * linv);
            *(f16x4*)&OP[((size_t)pb * 2048 + n) * 64 + df * 16 + g * 4] = *(f16x4*)o4;
        }
    }
}

// ---------------------------------------------------------------------------
// Kernel 3b: combine the three KV-parts -> AO [b, n, h*64+d] fp16.
// ---------------------------------------------------------------------------
__global__ void attn_combine(const f16* __restrict__ OP, const float* __restrict__ Mst,
                             const float* __restrict__ Lst, f16* __restrict__ AO) {
    const int tid = blockIdx.x * 256 + threadIdx.x;
    const int d4 = (tid & 15) * 4;
    const int pr = tid >> 4;          // bh*2048 + n
    const int bh = pr >> 11, n = pr & 2047;
    const int i0 = (bh * 3) * 2048 + n;
    const float m0 = Mst[i0], m1 = Mst[i0 + 2048], m2 = Mst[i0 + 4096];
    const float m = max3f(m0, m1, m2);
    const float c0 = fexp2(m0 - m) * Lst[i0];
    const float c1 = fexp2(m1 - m) * Lst[i0 + 2048];
    const float c2 = fexp2(m2 - m) * Lst[i0 + 4096];
    const float inv = 1.0f / (c0 + c1 + c2);
    f16x4 o0 = *(const f16x4*)(OP + (size_t)i0 * 64 + d4);
    f16x4 o1 = *(const f16x4*)(OP + (size_t)(i0 + 2048) * 64 + d4);
    f16x4 o2 = *(const f16x4*)(OP + (size_t)(i0 + 4096) * 64 + d4);
    const int b = bh / 12, h = bh - b * 12;
    f16 out[4];
#pragma unroll
    for (int j = 0; j < 4; ++j)
        out[j] = (f16)((c0 * (float)o0[j] + c1 * (float)o1[j] + c2 * (float)o2[j]) * inv);
    *(f16x4*)(AO + ((size_t)(b * 2048 + n)) * 768 + h * 64 + d4) = *(f16x4*)out;
}

// ---------------------------------------------------------------------------
// Kernel 4: out = AO @ Wfb^T + b_fc. 64x64 tiles, XOR-swizzled LDS,
// grid (64, 12) = 768 blocks. (R18 exact)
// ---------------------------------------------------------------------------
__global__ __launch_bounds__(256) void fc_gemm(const f16* __restrict__ A,
                                               const f16* __restrict__ Wfb,
                                               const float* __restrict__ bias,
                                               float* __restrict__ OUT) {
    __shared__ f16 As[64 * 64], Bs[64 * 64];
    const int t = threadIdx.x;
    const int lane = t & 63, wv = t >> 6;
    const int wm = (wv >> 1) * 32, wn = (wv & 1) * 32;
    const int r = lane & 15, g = lane >> 4;
    const int bm = blockIdx.x, bn = blockIdx.y;

    f32x4 acc[2][2];
#pragma unroll
    for (int i = 0; i < 2; ++i)
#pragma unroll
        for (int j = 0; j < 2; ++j) acc[i][j] = (f32x4)0.0f;

    const int srow = t >> 2;
    const int ssg = (t & 3) * 2;

    for (int ks = 0; ks < 768; ks += 64) {
        const f16* as = A + (size_t)(bm * 64 + srow) * 768 + ks;
        const f16* bs = Wfb + (size_t)(bn * 64 + srow) * 768 + ks;
#pragma unroll
        for (int u = 0; u < 2; ++u) {
            const int sg = ssg + u;
            const int dst = srow * 64 + ((sg ^ (srow & 7)) << 3);
            *(f16x8*)&As[dst] = *(const f16x8*)(as + sg * 8);
            *(f16x8*)&Bs[dst] = *(const f16x8*)(bs + sg * 8);
        }
        __syncthreads();

#pragma unroll
        for (int kc = 0; kc < 2; ++kc) {
            f16x8 a[2], b[2];
#pragma unroll
            for (int mf = 0; mf < 2; ++mf) {
                const int row = wm + mf * 16 + r;
                a[mf] = *(f16x8*)&As[row * 64 + (((kc * 4 + g) ^ (row & 7)) << 3)];
            }
#pragma unroll
            for (int nf = 0; nf < 2; ++nf) {
                const int row = wn + nf * 16 + r;
                b[nf] = *(f16x8*)&Bs[row * 64 + (((kc * 4 + g) ^ (row & 7)) << 3)];
            }
#pragma unroll
            for (int mf = 0; mf < 2; ++mf)
#pragma unroll
                for (int nf = 0; nf < 2; ++nf)
                    acc[mf][nf] = MFMA16(a[mf], b[nf], acc[mf][nf]);
        }
        __syncthreads();
    }

#pragma unroll
    for (int nf = 0; nf < 2; ++nf) {
        const int col = bn * 64 + wn + nf * 16 + r;
        const float bv = bias[col];
#pragma unroll
        for (int mf = 0; mf < 2; ++mf) {
            const int row = bm * 64 + wm + mf * 16 + g * 4;
#pragma unroll
            for (int v = 0; v < 4; ++v)
                OUT[(size_t)(row + v) * 768 + col] = acc[mf][nf][v] + bv;
        }
    }
}

// ---------------------------------------------------------------------------
extern "C" void kernel_launch(void* const* d_in, const int* in_sizes, int n_in,
                              void* d_out, int out_size, void* d_ws, size_t ws_size,
                              hipStream_t stream) {
    (void)in_sizes; (void)n_in; (void)out_size; (void)ws_size;
    const float* x     = (const float*)d_in[0];   // [2,2048,768]
    const float* w_qkv = (const float*)d_in[1];   // [2304,768]
    const float* w_fc  = (const float*)d_in[2];   // [768,768]
    const float* b_fc  = (const float*)d_in[3];   // [768]
    float* out = (float*)d_out;                   // [2,2048,768] fp32

    char* ws = (char*)d_ws;
    f16* Xh  = (f16*)ws;                         // 3,145,728 f16 each (6 MB):
    f16* Xl  = Xh + 3145728;
    f16* Qh  = Xl + 3145728;
    f16* Ql  = Qh + 3145728;
    f16* Khg = Ql + 3145728;
    f16* VTg = Khg + 3145728;
    f16* AO  = VTg + 3145728;
    f16* Wh  = AO + 3145728;                     // 1,769,472 f16
    f16* Wfb = Wh + 1769472;                     // 589,824 f16
    float* Mst = (float*)(Wfb + 589824);         // 147,456 floats (72 x 2048)
    float* Lst = Mst + 147456;
    f16* OP  = (f16*)(Lst + 147456);             // 9,437,184 f16
    // total = 68,812,800 B

    split_inputs<<<2688, 256, 0, stream>>>(x, w_qkv, w_fc, Xh, Xl, Wh, Wfb);
    qkv_gemm<<<dim3(64, 18), 256, 0, stream>>>(Xh, Xl, Wh, Qh, Ql, Khg, VTg);
    attn_partial<<<1152, 256, 0, stream>>>(Qh, Ql, Khg, VTg, OP, Mst, Lst);
    attn_combine<<<3072, 256, 0, stream>>>(OP, Mst, Lst, AO);
    fc_gemm<<<dim3(64, 12), 256, 0, stream>>>(AO, Wfb, b_fc, out);
}